// Round 1
// baseline (772.435 us; speedup 1.0000x reference)
//
#include <hip/hip_runtime.h>
#include <hip/hip_bf16.h>

typedef __attribute__((ext_vector_type(8))) short bf16x8;
typedef __attribute__((ext_vector_type(8))) unsigned short u16x8;
typedef __attribute__((ext_vector_type(4))) float f32x4;

__device__ __forceinline__ unsigned short f2b(float f) {
  union { float f; unsigned u; } c; c.f = f;
  return (unsigned short)((c.u + 0x7fffu + ((c.u >> 16) & 1u)) >> 16);
}

// ---------------- GEMM: C[M,128] = act(A[M,K] @ W[K,128] (+bias)) ----------------
// BM=128, BN=128, BK=64. 4 waves, each computes a 64x64 quadrant via 4x4 16x16x32 MFMAs.
template<int K, int ACT>
__global__ __launch_bounds__(256) void gemm_kernel(
    const float* __restrict__ A, int M,
    const float* __restrict__ W, const float* __restrict__ bias,
    float* __restrict__ C)
{
  constexpr int BK = 64;
  constexpr int LS = BK + 8;              // pad 8 bf16 (16B) -> 144B row stride
  __shared__ unsigned short As[128 * LS];
  __shared__ unsigned short Bs[128 * LS]; // stored transposed: Bs[col][k]
  const int t = threadIdx.x;
  const int lane = t & 63;
  const int wave = t >> 6;
  const int wr = wave >> 1, wc = wave & 1;
  const long row0 = (long)blockIdx.x * 128;

  f32x4 acc[4][4] = {};

  for (int k0 = 0; k0 < K; k0 += BK) {
    // stage A: 128x64 fp32 -> bf16 (coalesced float4 reads)
#pragma unroll
    for (int i = 0; i < 8; ++i) {
      int idx = t + i * 256;       // 2048 float4 units
      int r = idx >> 4;            // 0..127
      int kq = idx & 15;           // float4 within row
      long gr = row0 + r; if (gr >= M) gr = M - 1;   // clamp; write is guarded
      const float4 v = *(const float4*)(A + gr * K + k0 + kq * 4);
      ushort4 b;
      b.x = f2b(v.x); b.y = f2b(v.y); b.z = f2b(v.z); b.w = f2b(v.w);
      *(ushort4*)(&As[r * LS + kq * 4]) = b;
    }
    // stage B transposed: thread covers (col, k8): 8 k-consecutive elems for one col
#pragma unroll
    for (int i = 0; i < 4; ++i) {
      int idx = t + i * 256;       // 1024 units
      int col = idx & 127;
      int k8 = idx >> 7;           // 0..7
      u16x8 b;
#pragma unroll
      for (int j = 0; j < 8; ++j)
        b[j] = f2b(W[(long)(k0 + k8 * 8 + j) * 128 + col]);
      *(u16x8*)(&Bs[col * LS + k8 * 8]) = b;
    }
    __syncthreads();
#pragma unroll
    for (int kk = 0; kk < BK; kk += 32) {
      const int koff = kk + (lane >> 4) * 8;
      bf16x8 af[4], bfr[4];
#pragma unroll
      for (int m = 0; m < 4; ++m)
        af[m] = *(const bf16x8*)(&As[(wr * 64 + m * 16 + (lane & 15)) * LS + koff]);
#pragma unroll
      for (int n = 0; n < 4; ++n)
        bfr[n] = *(const bf16x8*)(&Bs[(wc * 64 + n * 16 + (lane & 15)) * LS + koff]);
#pragma unroll
      for (int m = 0; m < 4; ++m)
#pragma unroll
        for (int n = 0; n < 4; ++n)
          acc[m][n] = __builtin_amdgcn_mfma_f32_16x16x32_bf16(af[m], bfr[n], acc[m][n], 0, 0, 0);
    }
    __syncthreads();
  }

  // epilogue: C/D layout col=lane&15, row=(lane>>4)*4+reg
#pragma unroll
  for (int m = 0; m < 4; ++m) {
#pragma unroll
    for (int j = 0; j < 4; ++j) {
      long gr = row0 + wr * 64 + m * 16 + (lane >> 4) * 4 + j;
      if (gr < M) {
#pragma unroll
        for (int n = 0; n < 4; ++n) {
          int c = wc * 64 + n * 16 + (lane & 15);
          float v = acc[m][n][j];
          if (bias) v += bias[c];
          if (ACT == 1) v = fmaxf(v, 0.f);
          C[gr * 128 + c] = v;
        }
      }
    }
  }
}

// ---------------- attention logits: a_src/a_dst[n][head] ----------------
__global__ void attn_logits_kernel(const float* __restrict__ h, int N,
                                   const float* __restrict__ att_src,
                                   const float* __restrict__ att_dst,
                                   float* __restrict__ a_src, float* __restrict__ a_dst)
{
  int n = (blockIdx.x * blockDim.x + threadIdx.x) >> 6;
  int lane = threadIdx.x & 63;
  if (n >= N) return;
  const float2 hv = *(const float2*)(h + (size_t)n * 128 + lane * 2);
  const float2 as = *(const float2*)(att_src + lane * 2);
  const float2 ad = *(const float2*)(att_dst + lane * 2);
  float s = hv.x * as.x + hv.y * as.y;
  float d = hv.x * ad.x + hv.y * ad.y;
#pragma unroll
  for (int off = 1; off < 16; off <<= 1) {
    s += __shfl_xor(s, off);
    d += __shfl_xor(d, off);
  }
  if ((lane & 15) == 0) {
    int head = lane >> 4;
    a_src[(size_t)n * 4 + head] = s;
    a_dst[(size_t)n * 4 + head] = d;
  }
}

// ---------------- CSR build ----------------
__global__ void hist_kernel(const int* __restrict__ dst, int E, int* __restrict__ counts)
{
  int e = blockIdx.x * blockDim.x + threadIdx.x;
  if (e >= E) return;
  atomicAdd(&counts[dst[e]], 1);
}

__global__ __launch_bounds__(1024) void scan_pass1(const int* __restrict__ counts, int N,
                                                   int* __restrict__ excl, int* __restrict__ bsums)
{
  __shared__ int wsum[16];
  int t = threadIdx.x;
  int i = blockIdx.x * 1024 + t;
  int v = (i < N) ? counts[i] : 0;
  int x = v;
#pragma unroll
  for (int off = 1; off < 64; off <<= 1) {
    int y = __shfl_up(x, off);
    if ((t & 63) >= off) x += y;
  }
  if ((t & 63) == 63) wsum[t >> 6] = x;
  __syncthreads();
  if (t < 16) {
    int w = wsum[t];
#pragma unroll
    for (int off = 1; off < 16; off <<= 1) {
      int y = __shfl_up(w, off);
      if (t >= off) w += y;
    }
    wsum[t] = w;
  }
  __syncthreads();
  int add = (t >= 64) ? wsum[(t >> 6) - 1] : 0;
  int incl = x + add;
  if (i < N) excl[i] = incl - v;
  if (t == 1023) bsums[blockIdx.x] = incl;
}

__global__ __launch_bounds__(1024) void scan_pass2(int* __restrict__ bs, int NB, int* __restrict__ total_out)
{
  __shared__ int wsum[16];
  int t = threadIdx.x;
  int v = (t < NB) ? bs[t] : 0;
  int x = v;
#pragma unroll
  for (int off = 1; off < 64; off <<= 1) {
    int y = __shfl_up(x, off);
    if ((t & 63) >= off) x += y;
  }
  if ((t & 63) == 63) wsum[t >> 6] = x;
  __syncthreads();
  if (t < 16) {
    int w = wsum[t];
#pragma unroll
    for (int off = 1; off < 16; off <<= 1) {
      int y = __shfl_up(w, off);
      if (t >= off) w += y;
    }
    wsum[t] = w;
  }
  __syncthreads();
  int add = (t >= 64) ? wsum[(t >> 6) - 1] : 0;
  int incl = x + add;
  if (t < NB) bs[t] = incl - v;
  if (t == 1023) *total_out = incl;
}

__global__ __launch_bounds__(1024) void scan_pass3(int* __restrict__ excl, int N, const int* __restrict__ bs)
{
  int i = blockIdx.x * 1024 + threadIdx.x;
  if (i < N) excl[i] += bs[blockIdx.x];
}

__global__ void fill_csr_kernel(const int* __restrict__ src, const int* __restrict__ dst, int E,
                                const int* __restrict__ row_ptr, int* __restrict__ cur,
                                int* __restrict__ col_idx)
{
  int e = blockIdx.x * blockDim.x + threadIdx.x;
  if (e >= E) return;
  int d = dst[e];
  int pos = row_ptr[d] + atomicAdd(&cur[d], 1);
  col_idx[pos] = src[e];
}

// ---------------- fused GAT aggregation: softmax attention + weighted sum ----------------
// one wave per node; lane covers dims {2*lane, 2*lane+1}; head = lane>>4
__global__ void gat_aggregate_kernel(const float* __restrict__ h, const float* __restrict__ a_src,
                                     const float* __restrict__ a_dst, const int* __restrict__ row_ptr,
                                     const int* __restrict__ col_idx, const float* __restrict__ bias,
                                     int N, float* __restrict__ out)
{
  int n = (blockIdx.x * blockDim.x + threadIdx.x) >> 6;
  int lane = threadIdx.x & 63;
  if (n >= N) return;
  const int head = lane >> 4;
  const int beg = row_ptr[n], end = row_ptr[n + 1];
  const float adst = a_dst[(size_t)n * 4 + head];

  // pass 1: max logit per head (self-loop included)
  float slf = a_src[(size_t)n * 4 + head] + adst;
  slf = (slf > 0.f) ? slf : 0.2f * slf;
  float mx = slf;
  for (int e = beg + (lane & 15); e < end; e += 16) {
    int s = col_idx[e];
    float lg = a_src[(size_t)s * 4 + head] + adst;
    lg = (lg > 0.f) ? lg : 0.2f * lg;
    mx = fmaxf(mx, lg);
  }
#pragma unroll
  for (int off = 1; off < 16; off <<= 1) mx = fmaxf(mx, __shfl_xor(mx, off));

  // pass 2: denom + weighted accumulation (whole wave walks edges together)
  float p0 = __expf(slf - mx);
  float denom = p0;
  const float2 hs = *(const float2*)(h + (size_t)n * 128 + 2 * lane);
  float acc0 = p0 * hs.x, acc1 = p0 * hs.y;
  for (int e = beg; e < end; ++e) {
    int s = col_idx[e];
    float lg = a_src[(size_t)s * 4 + head] + adst;
    lg = (lg > 0.f) ? lg : 0.2f * lg;
    float p = __expf(lg - mx);
    denom += p;
    const float2 hv = *(const float2*)(h + (size_t)s * 128 + 2 * lane);
    acc0 += p * hv.x; acc1 += p * hv.y;
  }
  float inv = 1.0f / (denom + 1e-16f);
  float o0 = acc0 * inv + bias[2 * lane];
  float o1 = acc1 * inv + bias[2 * lane + 1];
  // ELU
  o0 = (o0 > 0.f) ? o0 : expm1f(o0);
  o1 = (o1 > 0.f) ? o1 : expm1f(o1);
  float2 r; r.x = o0; r.y = o1;
  *(float2*)(out + (size_t)n * 128 + 2 * lane) = r;
}

// ---------------- classifier: out = relu(x@Wc1+bc1)@Wc2+bc2 ----------------
__global__ void classifier_kernel(const float* __restrict__ x, const float* __restrict__ Wc1,
                                  const float* __restrict__ bc1, const float* __restrict__ Wc2,
                                  const float* __restrict__ bc2, float* __restrict__ out, int M)
{
  int row = (blockIdx.x * blockDim.x + threadIdx.x) >> 6;
  int lane = threadIdx.x & 63;
  if (row >= M) return;
  const float* xr = x + (size_t)row * 128;
  float c = 0.f;
#pragma unroll 8
  for (int k = 0; k < 128; ++k)
    c = fmaf(xr[k], Wc1[k * 64 + lane], c);
  c += bc1[lane];
  c = fmaxf(c, 0.f);
  float o0 = c * Wc2[lane * 2 + 0];
  float o1 = c * Wc2[lane * 2 + 1];
#pragma unroll
  for (int off = 1; off < 64; off <<= 1) {
    o0 += __shfl_xor(o0, off);
    o1 += __shfl_xor(o1, off);
  }
  if (lane == 0) {
    out[(size_t)row * 2 + 0] = o0 + bc2[0];
    out[(size_t)row * 2 + 1] = o1 + bc2[1];
  }
}

extern "C" void kernel_launch(void* const* d_in, const int* in_sizes, int n_in,
                              void* d_out, int out_size, void* d_ws, size_t ws_size,
                              hipStream_t stream)
{
  const float* x_news = (const float*)d_in[0];
  const float* x_tw   = (const float*)d_in[1];
  const int*   ei     = (const int*)d_in[2];
  const float* W_news = (const float*)d_in[3];
  const float* b_news = (const float*)d_in[4];
  const float* W_tw   = (const float*)d_in[5];
  const float* b_tw   = (const float*)d_in[6];
  const float* g1W  = (const float*)d_in[7];
  const float* g1as = (const float*)d_in[8];
  const float* g1ad = (const float*)d_in[9];
  const float* g1b  = (const float*)d_in[10];
  const float* g2W  = (const float*)d_in[11];
  const float* g2as = (const float*)d_in[12];
  const float* g2ad = (const float*)d_in[13];
  const float* g2b  = (const float*)d_in[14];
  const float* Wc1  = (const float*)d_in[15];
  const float* bc1  = (const float*)d_in[16];
  const float* Wc2  = (const float*)d_in[17];
  const float* bc2  = (const float*)d_in[18];

  const int n_news = in_sizes[0] / 768;
  const int n_tw   = in_sizes[1] / 512;
  const int N = n_news + n_tw;
  const int E = in_sizes[2] / 2;
  const int* src = ei;
  const int* dst = ei + E;

  char* ws = (char*)d_ws;
  size_t off = 0;
  auto alloc = [&](size_t bytes) -> void* {
    void* p = ws + off;
    off += (bytes + 255) & ~(size_t)255;
    return p;
  };
  float* x_feat  = (float*)alloc((size_t)N * 128 * 4);
  float* h_feat  = (float*)alloc((size_t)N * 128 * 4);
  float* a_src   = (float*)alloc((size_t)N * 4 * 4);
  float* a_dst   = (float*)alloc((size_t)N * 4 * 4);
  int*   row_ptr = (int*)alloc((size_t)(N + 1) * 4);
  int*   counts  = (int*)alloc((size_t)N * 4);
  int*   cur     = (int*)alloc((size_t)N * 4);
  int*   col_idx = (int*)alloc((size_t)E * 4);
  int*   bsums   = (int*)alloc(4096);

  hipMemsetAsync(counts, 0, (size_t)N * 4, stream);
  hipMemsetAsync(cur, 0, (size_t)N * 4, stream);

  // input linear layers (relu)
  gemm_kernel<768, 1><<<dim3((n_news + 127) / 128), 256, 0, stream>>>(x_news, n_news, W_news, b_news, x_feat);
  gemm_kernel<512, 1><<<dim3((n_tw + 127) / 128), 256, 0, stream>>>(x_tw, n_tw, W_tw, b_tw, x_feat + (size_t)n_news * 128);

  // CSR build (by dst), reused for both GAT layers
  hist_kernel<<<(E + 255) / 256, 256, 0, stream>>>(dst, E, counts);
  int NB = (N + 1023) / 1024;
  scan_pass1<<<NB, 1024, 0, stream>>>(counts, N, row_ptr, bsums);
  scan_pass2<<<1, 1024, 0, stream>>>(bsums, NB, row_ptr + N);
  scan_pass3<<<NB, 1024, 0, stream>>>(row_ptr, N, bsums);
  fill_csr_kernel<<<(E + 255) / 256, 256, 0, stream>>>(src, dst, E, row_ptr, cur, col_idx);

  // GAT layer 1
  gemm_kernel<128, 0><<<dim3((N + 127) / 128), 256, 0, stream>>>(x_feat, N, g1W, nullptr, h_feat);
  attn_logits_kernel<<<(N + 3) / 4, 256, 0, stream>>>(h_feat, N, g1as, g1ad, a_src, a_dst);
  gat_aggregate_kernel<<<(N + 3) / 4, 256, 0, stream>>>(h_feat, a_src, a_dst, row_ptr, col_idx, g1b, N, x_feat);

  // GAT layer 2
  gemm_kernel<128, 0><<<dim3((N + 127) / 128), 256, 0, stream>>>(x_feat, N, g2W, nullptr, h_feat);
  attn_logits_kernel<<<(N + 3) / 4, 256, 0, stream>>>(h_feat, N, g2as, g2ad, a_src, a_dst);
  gat_aggregate_kernel<<<(N + 3) / 4, 256, 0, stream>>>(h_feat, a_src, a_dst, row_ptr, col_idx, g2b, N, x_feat);

  // classifier on news rows
  classifier_kernel<<<(n_news + 3) / 4, 256, 0, stream>>>(x_feat, Wc1, bc1, Wc2, bc2, (float*)d_out, n_news);
}

// Round 2
// 633.894 us; speedup vs baseline: 1.2186x; 1.2186x over previous
//
#include <hip/hip_runtime.h>
#include <hip/hip_bf16.h>

typedef __attribute__((ext_vector_type(8))) short bf16x8;
typedef __attribute__((ext_vector_type(8))) unsigned short u16x8;
typedef __attribute__((ext_vector_type(4))) float f32x4;

__device__ __forceinline__ unsigned short f2b(float f) {
  union { float f; unsigned u; } c; c.f = f;
  return (unsigned short)((c.u + 0x7fffu + ((c.u >> 16) & 1u)) >> 16);
}

// ---------------- GEMM: C[M,128] = act(A[M,K] @ W[K,128] (+bias)) ----------------
// BM=128, BN=128, BK=64. 4 waves, each computes a 64x64 quadrant via 4x4 16x16x32 MFMAs.
// LOGITS=1: additionally emit a_src/a_dst[row][head] = sum_d C[row, head*32+d] * att[head][d]
//   (each (row, head) lives entirely in one wave: head = wc*2 + (n>>1))
template<int K, int ACT, int LOGITS>
__global__ __launch_bounds__(256) void gemm_kernel(
    const float* __restrict__ A, int M,
    const float* __restrict__ W, const float* __restrict__ bias,
    float* __restrict__ C,
    const float* __restrict__ att_src, const float* __restrict__ att_dst,
    float* __restrict__ a_src, float* __restrict__ a_dst)
{
  constexpr int BK = 64;
  constexpr int LS = BK + 8;              // pad 8 bf16 (16B) -> 144B row stride
  __shared__ unsigned short As[128 * LS];
  __shared__ unsigned short Bs[128 * LS]; // stored transposed: Bs[col][k]
  const int t = threadIdx.x;
  const int lane = t & 63;
  const int wave = t >> 6;
  const int wr = wave >> 1, wc = wave & 1;
  const long row0 = (long)blockIdx.x * 128;

  f32x4 acc[4][4] = {};

  for (int k0 = 0; k0 < K; k0 += BK) {
    // stage A: 128x64 fp32 -> bf16 (coalesced float4 reads)
#pragma unroll
    for (int i = 0; i < 8; ++i) {
      int idx = t + i * 256;       // 2048 float4 units
      int r = idx >> 4;            // 0..127
      int kq = idx & 15;           // float4 within row
      long gr = row0 + r; if (gr >= M) gr = M - 1;   // clamp; write is guarded
      const float4 v = *(const float4*)(A + gr * K + k0 + kq * 4);
      ushort4 b;
      b.x = f2b(v.x); b.y = f2b(v.y); b.z = f2b(v.z); b.w = f2b(v.w);
      *(ushort4*)(&As[r * LS + kq * 4]) = b;
    }
    // stage B transposed: thread covers (col, k8): 8 k-consecutive elems for one col
#pragma unroll
    for (int i = 0; i < 4; ++i) {
      int idx = t + i * 256;       // 1024 units
      int col = idx & 127;
      int k8 = idx >> 7;           // 0..7
      u16x8 b;
#pragma unroll
      for (int j = 0; j < 8; ++j)
        b[j] = f2b(W[(long)(k0 + k8 * 8 + j) * 128 + col]);
      *(u16x8*)(&Bs[col * LS + k8 * 8]) = b;
    }
    __syncthreads();
#pragma unroll
    for (int kk = 0; kk < BK; kk += 32) {
      const int koff = kk + (lane >> 4) * 8;
      bf16x8 af[4], bfr[4];
#pragma unroll
      for (int m = 0; m < 4; ++m)
        af[m] = *(const bf16x8*)(&As[(wr * 64 + m * 16 + (lane & 15)) * LS + koff]);
#pragma unroll
      for (int n = 0; n < 4; ++n)
        bfr[n] = *(const bf16x8*)(&Bs[(wc * 64 + n * 16 + (lane & 15)) * LS + koff]);
#pragma unroll
      for (int m = 0; m < 4; ++m)
#pragma unroll
        for (int n = 0; n < 4; ++n)
          acc[m][n] = __builtin_amdgcn_mfma_f32_16x16x32_bf16(af[m], bfr[n], acc[m][n], 0, 0, 0);
    }
    __syncthreads();
  }

  // attention-vector fragments for this wave's columns (only used if LOGITS)
  float asv[4], adv[4];
  if (LOGITS) {
#pragma unroll
    for (int n = 0; n < 4; ++n) {
      int hd = wc * 2 + (n >> 1);
      int dim = (n & 1) * 16 + (lane & 15);
      asv[n] = att_src[hd * 32 + dim];
      adv[n] = att_dst[hd * 32 + dim];
    }
  }

  // epilogue: C/D layout col=lane&15, row=(lane>>4)*4+reg
#pragma unroll
  for (int m = 0; m < 4; ++m) {
#pragma unroll
    for (int j = 0; j < 4; ++j) {
      long gr = row0 + wr * 64 + m * 16 + (lane >> 4) * 4 + j;
      if (gr < M) {
#pragma unroll
        for (int n = 0; n < 4; ++n) {
          int c = wc * 64 + n * 16 + (lane & 15);
          float v = acc[m][n][j];
          if (bias) v += bias[c];
          if (ACT == 1) v = fmaxf(v, 0.f);
          C[gr * 128 + c] = v;
        }
      }
      if (LOGITS) {
        // per-head partial dots: head_a = wc*2 (n=0,1), head_b = wc*2+1 (n=2,3)
        float sa = fmaf(acc[m][0][j], asv[0], acc[m][1][j] * asv[1]);
        float sb = fmaf(acc[m][2][j], asv[2], acc[m][3][j] * asv[3]);
        float da = fmaf(acc[m][0][j], adv[0], acc[m][1][j] * adv[1]);
        float db = fmaf(acc[m][2][j], adv[2], acc[m][3][j] * adv[3]);
#pragma unroll
        for (int off = 1; off < 16; off <<= 1) {
          sa += __shfl_xor(sa, off);
          sb += __shfl_xor(sb, off);
          da += __shfl_xor(da, off);
          db += __shfl_xor(db, off);
        }
        if ((lane & 15) == 0 && gr < M) {
          a_src[gr * 4 + wc * 2 + 0] = sa;
          a_src[gr * 4 + wc * 2 + 1] = sb;
          a_dst[gr * 4 + wc * 2 + 0] = da;
          a_dst[gr * 4 + wc * 2 + 1] = db;
        }
      }
    }
  }
}

// ---------------- CSR build ----------------
__global__ void hist_kernel(const int* __restrict__ dst, int E, int* __restrict__ counts)
{
  int e = blockIdx.x * blockDim.x + threadIdx.x;
  if (e >= E) return;
  atomicAdd(&counts[dst[e]], 1);
}

__global__ __launch_bounds__(1024) void scan_pass1(const int* __restrict__ counts, int N,
                                                   int* __restrict__ excl, int* __restrict__ bsums)
{
  __shared__ int wsum[16];
  int t = threadIdx.x;
  int i = blockIdx.x * 1024 + t;
  int v = (i < N) ? counts[i] : 0;
  int x = v;
#pragma unroll
  for (int off = 1; off < 64; off <<= 1) {
    int y = __shfl_up(x, off);
    if ((t & 63) >= off) x += y;
  }
  if ((t & 63) == 63) wsum[t >> 6] = x;
  __syncthreads();
  if (t < 16) {
    int w = wsum[t];
#pragma unroll
    for (int off = 1; off < 16; off <<= 1) {
      int y = __shfl_up(w, off);
      if (t >= off) w += y;
    }
    wsum[t] = w;
  }
  __syncthreads();
  int add = (t >= 64) ? wsum[(t >> 6) - 1] : 0;
  int incl = x + add;
  if (i < N) excl[i] = incl - v;
  if (t == 1023) bsums[blockIdx.x] = incl;
}

__global__ __launch_bounds__(1024) void scan_pass2(int* __restrict__ bs, int NB, int* __restrict__ total_out)
{
  __shared__ int wsum[16];
  int t = threadIdx.x;
  int v = (t < NB) ? bs[t] : 0;
  int x = v;
#pragma unroll
  for (int off = 1; off < 64; off <<= 1) {
    int y = __shfl_up(x, off);
    if ((t & 63) >= off) x += y;
  }
  if ((t & 63) == 63) wsum[t >> 6] = x;
  __syncthreads();
  if (t < 16) {
    int w = wsum[t];
#pragma unroll
    for (int off = 1; off < 16; off <<= 1) {
      int y = __shfl_up(w, off);
      if (t >= off) w += y;
    }
    wsum[t] = w;
  }
  __syncthreads();
  int add = (t >= 64) ? wsum[(t >> 6) - 1] : 0;
  int incl = x + add;
  if (t < NB) bs[t] = incl - v;
  if (t == 1023) *total_out = incl;
}

__global__ __launch_bounds__(1024) void scan_pass3(int* __restrict__ excl, int N, const int* __restrict__ bs)
{
  int i = blockIdx.x * 1024 + threadIdx.x;
  if (i < N) excl[i] += bs[blockIdx.x];
}

__global__ void fill_csr_kernel(const int* __restrict__ src, const int* __restrict__ dst, int E,
                                const int* __restrict__ row_ptr, int* __restrict__ cur,
                                int* __restrict__ col_idx)
{
  int e = blockIdx.x * blockDim.x + threadIdx.x;
  if (e >= E) return;
  int d = dst[e];
  int pos = row_ptr[d] + atomicAdd(&cur[d], 1);
  col_idx[pos] = src[e];
}

// ---------------- fused GAT aggregation: softmax attention + weighted sum ----------------
// one wave per node; lane covers dims {2*lane, 2*lane+1}; head = lane>>4
// No max-subtraction: alpha = exp(e)/sum exp(e) is mathematically identical to the
// max-shifted form; logits are O(1) so fp32 exp cannot overflow.
__global__ void gat_aggregate_kernel(const float* __restrict__ h, const float* __restrict__ a_src,
                                     const float* __restrict__ a_dst, const int* __restrict__ row_ptr,
                                     const int* __restrict__ col_idx, const float* __restrict__ bias,
                                     int N, float* __restrict__ out)
{
  int n = (blockIdx.x * blockDim.x + threadIdx.x) >> 6;
  int lane = threadIdx.x & 63;
  if (n >= N) return;
  const int head = lane >> 4;
  const int beg = row_ptr[n], end = row_ptr[n + 1];
  const float adst = a_dst[(size_t)n * 4 + head];

  // self loop
  float slf = a_src[(size_t)n * 4 + head] + adst;
  slf = (slf > 0.f) ? slf : 0.2f * slf;
  float ps = __expf(slf);
  float denom = ps;
  const float2 hs = *(const float2*)(h + (size_t)n * 128 + 2 * lane);
  float acc0 = ps * hs.x, acc1 = ps * hs.y;

  int e = beg;
  for (; e + 4 <= end; e += 4) {
    const int s0 = col_idx[e + 0];
    const int s1 = col_idx[e + 1];
    const int s2 = col_idx[e + 2];
    const int s3 = col_idx[e + 3];
    const float2 h0 = *(const float2*)(h + (size_t)s0 * 128 + 2 * lane);
    const float2 h1 = *(const float2*)(h + (size_t)s1 * 128 + 2 * lane);
    const float2 h2 = *(const float2*)(h + (size_t)s2 * 128 + 2 * lane);
    const float2 h3 = *(const float2*)(h + (size_t)s3 * 128 + 2 * lane);
    float l0 = a_src[(size_t)s0 * 4 + head] + adst;
    float l1 = a_src[(size_t)s1 * 4 + head] + adst;
    float l2 = a_src[(size_t)s2 * 4 + head] + adst;
    float l3 = a_src[(size_t)s3 * 4 + head] + adst;
    l0 = (l0 > 0.f) ? l0 : 0.2f * l0;
    l1 = (l1 > 0.f) ? l1 : 0.2f * l1;
    l2 = (l2 > 0.f) ? l2 : 0.2f * l2;
    l3 = (l3 > 0.f) ? l3 : 0.2f * l3;
    const float p0 = __expf(l0);
    const float p1 = __expf(l1);
    const float p2 = __expf(l2);
    const float p3 = __expf(l3);
    denom += (p0 + p1) + (p2 + p3);
    acc0 = fmaf(p0, h0.x, acc0); acc1 = fmaf(p0, h0.y, acc1);
    acc0 = fmaf(p1, h1.x, acc0); acc1 = fmaf(p1, h1.y, acc1);
    acc0 = fmaf(p2, h2.x, acc0); acc1 = fmaf(p2, h2.y, acc1);
    acc0 = fmaf(p3, h3.x, acc0); acc1 = fmaf(p3, h3.y, acc1);
  }
  for (; e < end; ++e) {
    const int s = col_idx[e];
    float lg = a_src[(size_t)s * 4 + head] + adst;
    lg = (lg > 0.f) ? lg : 0.2f * lg;
    const float p = __expf(lg);
    const float2 hv = *(const float2*)(h + (size_t)s * 128 + 2 * lane);
    denom += p;
    acc0 = fmaf(p, hv.x, acc0); acc1 = fmaf(p, hv.y, acc1);
  }
  float inv = 1.0f / (denom + 1e-16f);
  float o0 = acc0 * inv + bias[2 * lane];
  float o1 = acc1 * inv + bias[2 * lane + 1];
  // ELU
  o0 = (o0 > 0.f) ? o0 : expm1f(o0);
  o1 = (o1 > 0.f) ? o1 : expm1f(o1);
  float2 r; r.x = o0; r.y = o1;
  *(float2*)(out + (size_t)n * 128 + 2 * lane) = r;
}

// ---------------- classifier: out = relu(x@Wc1+bc1)@Wc2+bc2 ----------------
__global__ void classifier_kernel(const float* __restrict__ x, const float* __restrict__ Wc1,
                                  const float* __restrict__ bc1, const float* __restrict__ Wc2,
                                  const float* __restrict__ bc2, float* __restrict__ out, int M)
{
  int row = (blockIdx.x * blockDim.x + threadIdx.x) >> 6;
  int lane = threadIdx.x & 63;
  if (row >= M) return;
  const float* xr = x + (size_t)row * 128;
  float c = 0.f;
#pragma unroll 8
  for (int k = 0; k < 128; ++k)
    c = fmaf(xr[k], Wc1[k * 64 + lane], c);
  c += bc1[lane];
  c = fmaxf(c, 0.f);
  float o0 = c * Wc2[lane * 2 + 0];
  float o1 = c * Wc2[lane * 2 + 1];
#pragma unroll
  for (int off = 1; off < 64; off <<= 1) {
    o0 += __shfl_xor(o0, off);
    o1 += __shfl_xor(o1, off);
  }
  if (lane == 0) {
    out[(size_t)row * 2 + 0] = o0 + bc2[0];
    out[(size_t)row * 2 + 1] = o1 + bc2[1];
  }
}

extern "C" void kernel_launch(void* const* d_in, const int* in_sizes, int n_in,
                              void* d_out, int out_size, void* d_ws, size_t ws_size,
                              hipStream_t stream)
{
  const float* x_news = (const float*)d_in[0];
  const float* x_tw   = (const float*)d_in[1];
  const int*   ei     = (const int*)d_in[2];
  const float* W_news = (const float*)d_in[3];
  const float* b_news = (const float*)d_in[4];
  const float* W_tw   = (const float*)d_in[5];
  const float* b_tw   = (const float*)d_in[6];
  const float* g1W  = (const float*)d_in[7];
  const float* g1as = (const float*)d_in[8];
  const float* g1ad = (const float*)d_in[9];
  const float* g1b  = (const float*)d_in[10];
  const float* g2W  = (const float*)d_in[11];
  const float* g2as = (const float*)d_in[12];
  const float* g2ad = (const float*)d_in[13];
  const float* g2b  = (const float*)d_in[14];
  const float* Wc1  = (const float*)d_in[15];
  const float* bc1  = (const float*)d_in[16];
  const float* Wc2  = (const float*)d_in[17];
  const float* bc2  = (const float*)d_in[18];

  const int n_news = in_sizes[0] / 768;
  const int n_tw   = in_sizes[1] / 512;
  const int N = n_news + n_tw;
  const int E = in_sizes[2] / 2;
  const int* src = ei;
  const int* dst = ei + E;

  char* ws = (char*)d_ws;
  size_t off = 0;
  auto alloc = [&](size_t bytes) -> void* {
    void* p = ws + off;
    off += (bytes + 255) & ~(size_t)255;
    return p;
  };
  float* x_feat  = (float*)alloc((size_t)N * 128 * 4);
  float* h_feat  = (float*)alloc((size_t)N * 128 * 4);
  float* a_src   = (float*)alloc((size_t)N * 4 * 4);
  float* a_dst   = (float*)alloc((size_t)N * 4 * 4);
  int*   row_ptr = (int*)alloc((size_t)(N + 1) * 4);
  int*   counts  = (int*)alloc((size_t)N * 4);
  int*   cur     = (int*)alloc((size_t)N * 4);
  int*   col_idx = (int*)alloc((size_t)E * 4);
  int*   bsums   = (int*)alloc(4096);

  hipMemsetAsync(counts, 0, (size_t)N * 4, stream);
  hipMemsetAsync(cur, 0, (size_t)N * 4, stream);

  // input linear layers (relu)
  gemm_kernel<768, 1, 0><<<dim3((n_news + 127) / 128), 256, 0, stream>>>(
      x_news, n_news, W_news, b_news, x_feat, nullptr, nullptr, nullptr, nullptr);
  gemm_kernel<512, 1, 0><<<dim3((n_tw + 127) / 128), 256, 0, stream>>>(
      x_tw, n_tw, W_tw, b_tw, x_feat + (size_t)n_news * 128, nullptr, nullptr, nullptr, nullptr);

  // CSR build (by dst), reused for both GAT layers
  hist_kernel<<<(E + 255) / 256, 256, 0, stream>>>(dst, E, counts);
  int NB = (N + 1023) / 1024;
  scan_pass1<<<NB, 1024, 0, stream>>>(counts, N, row_ptr, bsums);
  scan_pass2<<<1, 1024, 0, stream>>>(bsums, NB, row_ptr + N);
  scan_pass3<<<NB, 1024, 0, stream>>>(row_ptr, N, bsums);
  fill_csr_kernel<<<(E + 255) / 256, 256, 0, stream>>>(src, dst, E, row_ptr, cur, col_idx);

  // GAT layer 1 (GEMM + fused attention logits)
  gemm_kernel<128, 0, 1><<<dim3((N + 127) / 128), 256, 0, stream>>>(
      x_feat, N, g1W, nullptr, h_feat, g1as, g1ad, a_src, a_dst);
  gat_aggregate_kernel<<<(N + 3) / 4, 256, 0, stream>>>(h_feat, a_src, a_dst, row_ptr, col_idx, g1b, N, x_feat);

  // GAT layer 2
  gemm_kernel<128, 0, 1><<<dim3((N + 127) / 128), 256, 0, stream>>>(
      x_feat, N, g2W, nullptr, h_feat, g2as, g2ad, a_src, a_dst);
  gat_aggregate_kernel<<<(N + 3) / 4, 256, 0, stream>>>(h_feat, a_src, a_dst, row_ptr, col_idx, g2b, N, x_feat);

  // classifier on news rows
  classifier_kernel<<<(n_news + 3) / 4, 256, 0, stream>>>(x_feat, Wc1, bc1, Wc2, bc2, (float*)d_out, n_news);
}

// Round 3
// 502.546 us; speedup vs baseline: 1.5370x; 1.2614x over previous
//
#include <hip/hip_runtime.h>
#include <hip/hip_bf16.h>
#include <type_traits>

typedef __attribute__((ext_vector_type(8))) short bf16x8;
typedef __attribute__((ext_vector_type(8))) unsigned short u16x8;
typedef __attribute__((ext_vector_type(4))) float f32x4;

__device__ __forceinline__ unsigned short f2b(float f) {
  union { float f; unsigned u; } c; c.f = f;
  return (unsigned short)((c.u + 0x7fffu + ((c.u >> 16) & 1u)) >> 16);
}
__device__ __forceinline__ float b2f_lo(unsigned v) { return __uint_as_float(v << 16); }
__device__ __forceinline__ float b2f_hi(unsigned v) { return __uint_as_float(v & 0xffff0000u); }

// ---------------- GEMM: C[M,128] = act(A[M,K] @ W[K,128] (+bias)), C in bf16 ----------------
// BM=128, BN=128, BK=64. 4 waves, each computes a 64x64 quadrant via 4x4 16x16x32 MFMAs.
// AT = float (stage converts to bf16) or unsigned short (bf16 passthrough).
// LOGITS=1: emit a_src/a_dst[row][head] = sum_d C[row, head*32+d] * att[head][d]
template<int K, int ACT, int LOGITS, typename AT>
__global__ __launch_bounds__(256) void gemm_kernel(
    const AT* __restrict__ A, int M,
    const float* __restrict__ W, const float* __restrict__ bias,
    unsigned short* __restrict__ C,
    const float* __restrict__ att_src, const float* __restrict__ att_dst,
    float* __restrict__ a_src, float* __restrict__ a_dst)
{
  constexpr int BK = 64;
  constexpr int LS = BK + 8;              // pad 8 bf16 (16B) -> 144B row stride
  __shared__ unsigned short As[128 * LS];
  __shared__ unsigned short Bs[128 * LS]; // stored transposed: Bs[col][k]
  const int t = threadIdx.x;
  const int lane = t & 63;
  const int wave = t >> 6;
  const int wr = wave >> 1, wc = wave & 1;
  const long row0 = (long)blockIdx.x * 128;

  f32x4 acc[4][4] = {};

  for (int k0 = 0; k0 < K; k0 += BK) {
    if constexpr (std::is_same<AT, float>::value) {
      // stage A: 128x64 fp32 -> bf16 (coalesced float4 reads)
#pragma unroll
      for (int i = 0; i < 8; ++i) {
        int idx = t + i * 256;       // 2048 float4 units
        int r = idx >> 4;            // 0..127
        int kq = idx & 15;           // float4 within row
        long gr = row0 + r; if (gr >= M) gr = M - 1;   // clamp; write is guarded
        const float4 v = *(const float4*)(A + gr * K + k0 + kq * 4);
        ushort4 b;
        b.x = f2b(v.x); b.y = f2b(v.y); b.z = f2b(v.z); b.w = f2b(v.w);
        *(ushort4*)(&As[r * LS + kq * 4]) = b;
      }
    } else {
      // stage A: 128x64 bf16 passthrough (16B loads)
#pragma unroll
      for (int i = 0; i < 4; ++i) {
        int idx = t + i * 256;       // 1024 ushort8 units
        int r = idx >> 3;            // 0..127
        int k8 = idx & 7;
        long gr = row0 + r; if (gr >= M) gr = M - 1;
        u16x8 v = *(const u16x8*)(A + gr * K + k0 + k8 * 8);
        *(u16x8*)(&As[r * LS + k8 * 8]) = v;
      }
    }
    // stage B transposed: thread covers (col, k8): 8 k-consecutive elems for one col
#pragma unroll
    for (int i = 0; i < 4; ++i) {
      int idx = t + i * 256;       // 1024 units
      int col = idx & 127;
      int k8 = idx >> 7;           // 0..7
      u16x8 b;
#pragma unroll
      for (int j = 0; j < 8; ++j)
        b[j] = f2b(W[(long)(k0 + k8 * 8 + j) * 128 + col]);
      *(u16x8*)(&Bs[col * LS + k8 * 8]) = b;
    }
    __syncthreads();
#pragma unroll
    for (int kk = 0; kk < BK; kk += 32) {
      const int koff = kk + (lane >> 4) * 8;
      bf16x8 af[4], bfr[4];
#pragma unroll
      for (int m = 0; m < 4; ++m)
        af[m] = *(const bf16x8*)(&As[(wr * 64 + m * 16 + (lane & 15)) * LS + koff]);
#pragma unroll
      for (int n = 0; n < 4; ++n)
        bfr[n] = *(const bf16x8*)(&Bs[(wc * 64 + n * 16 + (lane & 15)) * LS + koff]);
#pragma unroll
      for (int m = 0; m < 4; ++m)
#pragma unroll
        for (int n = 0; n < 4; ++n)
          acc[m][n] = __builtin_amdgcn_mfma_f32_16x16x32_bf16(af[m], bfr[n], acc[m][n], 0, 0, 0);
    }
    __syncthreads();
  }

  // attention-vector fragments for this wave's columns (only used if LOGITS)
  float asv[4], adv[4];
  if (LOGITS) {
#pragma unroll
    for (int n = 0; n < 4; ++n) {
      int hd = wc * 2 + (n >> 1);
      int dim = (n & 1) * 16 + (lane & 15);
      asv[n] = att_src[hd * 32 + dim];
      adv[n] = att_dst[hd * 32 + dim];
    }
  }

  // epilogue: C/D layout col=lane&15, row=(lane>>4)*4+reg
#pragma unroll
  for (int m = 0; m < 4; ++m) {
#pragma unroll
    for (int j = 0; j < 4; ++j) {
      long gr = row0 + wr * 64 + m * 16 + (lane >> 4) * 4 + j;
      if (gr < M) {
#pragma unroll
        for (int n = 0; n < 4; ++n) {
          int c = wc * 64 + n * 16 + (lane & 15);
          float v = acc[m][n][j];
          if (bias) v += bias[c];
          if (ACT == 1) v = fmaxf(v, 0.f);
          C[gr * 128 + c] = f2b(v);
        }
      }
      if (LOGITS) {
        // per-head partial dots: head_a = wc*2 (n=0,1), head_b = wc*2+1 (n=2,3)
        float sa = fmaf(acc[m][0][j], asv[0], acc[m][1][j] * asv[1]);
        float sb = fmaf(acc[m][2][j], asv[2], acc[m][3][j] * asv[3]);
        float da = fmaf(acc[m][0][j], adv[0], acc[m][1][j] * adv[1]);
        float db = fmaf(acc[m][2][j], adv[2], acc[m][3][j] * adv[3]);
#pragma unroll
        for (int off = 1; off < 16; off <<= 1) {
          sa += __shfl_xor(sa, off);
          sb += __shfl_xor(sb, off);
          da += __shfl_xor(da, off);
          db += __shfl_xor(db, off);
        }
        if ((lane & 15) == 0 && gr < M) {
          a_src[gr * 4 + wc * 2 + 0] = sa;
          a_src[gr * 4 + wc * 2 + 1] = sb;
          a_dst[gr * 4 + wc * 2 + 0] = da;
          a_dst[gr * 4 + wc * 2 + 1] = db;
        }
      }
    }
  }
}

// ---------------- CSR build ----------------
__global__ void hist_kernel(const int* __restrict__ dst, int E, int* __restrict__ counts)
{
  int e = blockIdx.x * blockDim.x + threadIdx.x;
  if (e >= E) return;
  atomicAdd(&counts[dst[e]], 1);
}

__global__ __launch_bounds__(1024) void scan_pass1(const int* __restrict__ counts, int N,
                                                   int* __restrict__ excl, int* __restrict__ bsums)
{
  __shared__ int wsum[16];
  int t = threadIdx.x;
  int i = blockIdx.x * 1024 + t;
  int v = (i < N) ? counts[i] : 0;
  int x = v;
#pragma unroll
  for (int off = 1; off < 64; off <<= 1) {
    int y = __shfl_up(x, off);
    if ((t & 63) >= off) x += y;
  }
  if ((t & 63) == 63) wsum[t >> 6] = x;
  __syncthreads();
  if (t < 16) {
    int w = wsum[t];
#pragma unroll
    for (int off = 1; off < 16; off <<= 1) {
      int y = __shfl_up(w, off);
      if (t >= off) w += y;
    }
    wsum[t] = w;
  }
  __syncthreads();
  int add = (t >= 64) ? wsum[(t >> 6) - 1] : 0;
  int incl = x + add;
  if (i < N) excl[i] = incl - v;
  if (t == 1023) bsums[blockIdx.x] = incl;
}

__global__ __launch_bounds__(1024) void scan_pass2(int* __restrict__ bs, int NB, int* __restrict__ total_out)
{
  __shared__ int wsum[16];
  int t = threadIdx.x;
  int v = (t < NB) ? bs[t] : 0;
  int x = v;
#pragma unroll
  for (int off = 1; off < 64; off <<= 1) {
    int y = __shfl_up(x, off);
    if ((t & 63) >= off) x += y;
  }
  if ((t & 63) == 63) wsum[t >> 6] = x;
  __syncthreads();
  if (t < 16) {
    int w = wsum[t];
#pragma unroll
    for (int off = 1; off < 16; off <<= 1) {
      int y = __shfl_up(w, off);
      if (t >= off) w += y;
    }
    wsum[t] = w;
  }
  __syncthreads();
  int add = (t >= 64) ? wsum[(t >> 6) - 1] : 0;
  int incl = x + add;
  if (t < NB) bs[t] = incl - v;
  if (t == 1023) *total_out = incl;
}

__global__ __launch_bounds__(1024) void scan_pass3(int* __restrict__ excl, int N, const int* __restrict__ bs)
{
  int i = blockIdx.x * 1024 + threadIdx.x;
  if (i < N) excl[i] += bs[blockIdx.x];
}

__global__ void fill_csr_kernel(const int* __restrict__ src, const int* __restrict__ dst, int E,
                                const int* __restrict__ row_ptr, int* __restrict__ cur,
                                int* __restrict__ col_idx)
{
  int e = blockIdx.x * blockDim.x + threadIdx.x;
  if (e >= E) return;
  int d = dst[e];
  int pos = row_ptr[d] + atomicAdd(&cur[d], 1);
  col_idx[pos] = src[e];
}

// ---------------- fused GAT aggregation (bf16 h): softmax attention + weighted sum ----------------
// one wave per node; lane covers dims {2*lane, 2*lane+1} via one 4B load; head = lane>>4
// No max-subtraction: logits are O(1), exp(e)/sum exp(e) == max-shifted form exactly.
__global__ void gat_aggregate_kernel(const unsigned short* __restrict__ h, const float* __restrict__ a_src,
                                     const float* __restrict__ a_dst, const int* __restrict__ row_ptr,
                                     const int* __restrict__ col_idx, const float* __restrict__ bias,
                                     int N, unsigned short* __restrict__ out)
{
  int n = (blockIdx.x * blockDim.x + threadIdx.x) >> 6;
  int lane = threadIdx.x & 63;
  if (n >= N) return;
  const int head = lane >> 4;
  const int beg = row_ptr[n], end = row_ptr[n + 1];
  const float adst = a_dst[(size_t)n * 4 + head];

  // self loop
  float slf = a_src[(size_t)n * 4 + head] + adst;
  slf = (slf > 0.f) ? slf : 0.2f * slf;
  float ps = __expf(slf);
  float denom = ps;
  const unsigned hs = *(const unsigned*)(h + (size_t)n * 128 + 2 * lane);
  float acc0 = ps * b2f_lo(hs), acc1 = ps * b2f_hi(hs);

  int e = beg;
  for (; e + 4 <= end; e += 4) {
    const int s0 = col_idx[e + 0];
    const int s1 = col_idx[e + 1];
    const int s2 = col_idx[e + 2];
    const int s3 = col_idx[e + 3];
    const unsigned h0 = *(const unsigned*)(h + (size_t)s0 * 128 + 2 * lane);
    const unsigned h1 = *(const unsigned*)(h + (size_t)s1 * 128 + 2 * lane);
    const unsigned h2 = *(const unsigned*)(h + (size_t)s2 * 128 + 2 * lane);
    const unsigned h3 = *(const unsigned*)(h + (size_t)s3 * 128 + 2 * lane);
    float l0 = a_src[(size_t)s0 * 4 + head] + adst;
    float l1 = a_src[(size_t)s1 * 4 + head] + adst;
    float l2 = a_src[(size_t)s2 * 4 + head] + adst;
    float l3 = a_src[(size_t)s3 * 4 + head] + adst;
    l0 = (l0 > 0.f) ? l0 : 0.2f * l0;
    l1 = (l1 > 0.f) ? l1 : 0.2f * l1;
    l2 = (l2 > 0.f) ? l2 : 0.2f * l2;
    l3 = (l3 > 0.f) ? l3 : 0.2f * l3;
    const float p0 = __expf(l0);
    const float p1 = __expf(l1);
    const float p2 = __expf(l2);
    const float p3 = __expf(l3);
    denom += (p0 + p1) + (p2 + p3);
    acc0 = fmaf(p0, b2f_lo(h0), acc0); acc1 = fmaf(p0, b2f_hi(h0), acc1);
    acc0 = fmaf(p1, b2f_lo(h1), acc0); acc1 = fmaf(p1, b2f_hi(h1), acc1);
    acc0 = fmaf(p2, b2f_lo(h2), acc0); acc1 = fmaf(p2, b2f_hi(h2), acc1);
    acc0 = fmaf(p3, b2f_lo(h3), acc0); acc1 = fmaf(p3, b2f_hi(h3), acc1);
  }
  for (; e < end; ++e) {
    const int s = col_idx[e];
    float lg = a_src[(size_t)s * 4 + head] + adst;
    lg = (lg > 0.f) ? lg : 0.2f * lg;
    const float p = __expf(lg);
    const unsigned hv = *(const unsigned*)(h + (size_t)s * 128 + 2 * lane);
    denom += p;
    acc0 = fmaf(p, b2f_lo(hv), acc0); acc1 = fmaf(p, b2f_hi(hv), acc1);
  }
  float inv = 1.0f / (denom + 1e-16f);
  float o0 = acc0 * inv + bias[2 * lane];
  float o1 = acc1 * inv + bias[2 * lane + 1];
  // ELU
  o0 = (o0 > 0.f) ? o0 : expm1f(o0);
  o1 = (o1 > 0.f) ? o1 : expm1f(o1);
  unsigned packed = (unsigned)f2b(o0) | ((unsigned)f2b(o1) << 16);
  *(unsigned*)(out + (size_t)n * 128 + 2 * lane) = packed;
}

// ---------------- classifier: out = relu(x@Wc1+bc1)@Wc2+bc2, x in bf16 ----------------
__global__ void classifier_kernel(const unsigned short* __restrict__ x, const float* __restrict__ Wc1,
                                  const float* __restrict__ bc1, const float* __restrict__ Wc2,
                                  const float* __restrict__ bc2, float* __restrict__ out, int M)
{
  int row = (blockIdx.x * blockDim.x + threadIdx.x) >> 6;
  int lane = threadIdx.x & 63;
  if (row >= M) return;
  const unsigned short* xr = x + (size_t)row * 128;
  float c = 0.f;
#pragma unroll 8
  for (int k = 0; k < 128; k += 2) {
    unsigned v = *(const unsigned*)(xr + k);
    c = fmaf(b2f_lo(v), Wc1[k * 64 + lane], c);
    c = fmaf(b2f_hi(v), Wc1[(k + 1) * 64 + lane], c);
  }
  c += bc1[lane];
  c = fmaxf(c, 0.f);
  float o0 = c * Wc2[lane * 2 + 0];
  float o1 = c * Wc2[lane * 2 + 1];
#pragma unroll
  for (int off = 1; off < 64; off <<= 1) {
    o0 += __shfl_xor(o0, off);
    o1 += __shfl_xor(o1, off);
  }
  if (lane == 0) {
    out[(size_t)row * 2 + 0] = o0 + bc2[0];
    out[(size_t)row * 2 + 1] = o1 + bc2[1];
  }
}

extern "C" void kernel_launch(void* const* d_in, const int* in_sizes, int n_in,
                              void* d_out, int out_size, void* d_ws, size_t ws_size,
                              hipStream_t stream)
{
  const float* x_news = (const float*)d_in[0];
  const float* x_tw   = (const float*)d_in[1];
  const int*   ei     = (const int*)d_in[2];
  const float* W_news = (const float*)d_in[3];
  const float* b_news = (const float*)d_in[4];
  const float* W_tw   = (const float*)d_in[5];
  const float* b_tw   = (const float*)d_in[6];
  const float* g1W  = (const float*)d_in[7];
  const float* g1as = (const float*)d_in[8];
  const float* g1ad = (const float*)d_in[9];
  const float* g1b  = (const float*)d_in[10];
  const float* g2W  = (const float*)d_in[11];
  const float* g2as = (const float*)d_in[12];
  const float* g2ad = (const float*)d_in[13];
  const float* g2b  = (const float*)d_in[14];
  const float* Wc1  = (const float*)d_in[15];
  const float* bc1  = (const float*)d_in[16];
  const float* Wc2  = (const float*)d_in[17];
  const float* bc2  = (const float*)d_in[18];

  const int n_news = in_sizes[0] / 768;
  const int n_tw   = in_sizes[1] / 512;
  const int N = n_news + n_tw;
  const int E = in_sizes[2] / 2;
  const int* src = ei;
  const int* dst = ei + E;

  char* ws = (char*)d_ws;
  size_t off = 0;
  auto alloc = [&](size_t bytes) -> void* {
    void* p = ws + off;
    off += (bytes + 255) & ~(size_t)255;
    return p;
  };
  unsigned short* x_feat = (unsigned short*)alloc((size_t)N * 128 * 2);
  unsigned short* h_feat = (unsigned short*)alloc((size_t)N * 128 * 2);
  float* a_src   = (float*)alloc((size_t)N * 4 * 4);
  float* a_dst   = (float*)alloc((size_t)N * 4 * 4);
  int*   row_ptr = (int*)alloc((size_t)(N + 1) * 4);
  int*   counts  = (int*)alloc((size_t)N * 4);
  int*   cur     = (int*)alloc((size_t)N * 4);
  int*   col_idx = (int*)alloc((size_t)E * 4);
  int*   bsums   = (int*)alloc(4096);

  hipMemsetAsync(counts, 0, (size_t)N * 4, stream);
  hipMemsetAsync(cur, 0, (size_t)N * 4, stream);

  // input linear layers (relu), output bf16
  gemm_kernel<768, 1, 0, float><<<dim3((n_news + 127) / 128), 256, 0, stream>>>(
      x_news, n_news, W_news, b_news, x_feat, nullptr, nullptr, nullptr, nullptr);
  gemm_kernel<512, 1, 0, float><<<dim3((n_tw + 127) / 128), 256, 0, stream>>>(
      x_tw, n_tw, W_tw, b_tw, x_feat + (size_t)n_news * 128, nullptr, nullptr, nullptr, nullptr);

  // CSR build (by dst), reused for both GAT layers
  hist_kernel<<<(E + 255) / 256, 256, 0, stream>>>(dst, E, counts);
  int NB = (N + 1023) / 1024;
  scan_pass1<<<NB, 1024, 0, stream>>>(counts, N, row_ptr, bsums);
  scan_pass2<<<1, 1024, 0, stream>>>(bsums, NB, row_ptr + N);
  scan_pass3<<<NB, 1024, 0, stream>>>(row_ptr, N, bsums);
  fill_csr_kernel<<<(E + 255) / 256, 256, 0, stream>>>(src, dst, E, row_ptr, cur, col_idx);

  // GAT layer 1 (bf16 A GEMM + fused attention logits)
  gemm_kernel<128, 0, 1, unsigned short><<<dim3((N + 127) / 128), 256, 0, stream>>>(
      x_feat, N, g1W, nullptr, h_feat, g1as, g1ad, a_src, a_dst);
  gat_aggregate_kernel<<<(N + 3) / 4, 256, 0, stream>>>(h_feat, a_src, a_dst, row_ptr, col_idx, g1b, N, x_feat);

  // GAT layer 2
  gemm_kernel<128, 0, 1, unsigned short><<<dim3((N + 127) / 128), 256, 0, stream>>>(
      x_feat, N, g2W, nullptr, h_feat, g2as, g2ad, a_src, a_dst);
  gat_aggregate_kernel<<<(N + 3) / 4, 256, 0, stream>>>(h_feat, a_src, a_dst, row_ptr, col_idx, g2b, N, x_feat);

  // classifier on news rows (bf16 x)
  classifier_kernel<<<(n_news + 3) / 4, 256, 0, stream>>>(x_feat, Wc1, bc1, Wc2, bc2, (float*)d_out, n_news);
}